// Round 1
// baseline (943.106 us; speedup 1.0000x reference)
//
#include <hip/hip_runtime.h>
#include <stdint.h>
#include <math.h>

#define NTOK 8192
#define DIM  1024
#define FDIM 4096
#define NEXP 8

typedef __bf16 bf16x8 __attribute__((ext_vector_type(8)));
typedef float floatx4 __attribute__((ext_vector_type(4)));

__device__ __forceinline__ unsigned short f2b(float f) {
  union { float f; unsigned u; } v; v.f = f;
  return (unsigned short)((v.u + 0x7fffu + ((v.u >> 16) & 1u)) >> 16);
}

// ---------------- router: logits, argmax, gate, counts ----------------
__global__ __launch_bounds__(256) void router_k(
    const float* __restrict__ x, const float* __restrict__ Wr,
    const float* __restrict__ br, int* __restrict__ idx,
    float* __restrict__ gate, int* __restrict__ ctrl) {
  int t = (int)((blockIdx.x * 256 + threadIdx.x) >> 6);
  int lane = threadIdx.x & 63;
  const float* xr = x + (size_t)t * DIM;
  float acc[NEXP];
#pragma unroll
  for (int e = 0; e < NEXP; e++) acc[e] = 0.f;
#pragma unroll
  for (int k = 0; k < DIM / 64; k++) {
    int d = k * 64 + lane;
    float xv = xr[d];
    const float4* wp = (const float4*)(Wr + (size_t)d * NEXP);
    float4 w0 = wp[0], w1 = wp[1];
    acc[0] += xv * w0.x; acc[1] += xv * w0.y;
    acc[2] += xv * w0.z; acc[3] += xv * w0.w;
    acc[4] += xv * w1.x; acc[5] += xv * w1.y;
    acc[6] += xv * w1.z; acc[7] += xv * w1.w;
  }
#pragma unroll
  for (int off = 32; off > 0; off >>= 1) {
#pragma unroll
    for (int e = 0; e < NEXP; e++) acc[e] += __shfl_xor(acc[e], off, 64);
  }
  if (lane == 0) {
    float mx = -3.4e38f; int best = 0;
#pragma unroll
    for (int e = 0; e < NEXP; e++) {
      float l = acc[e] + br[e];
      if (l > mx) { mx = l; best = e; }   // '>' keeps first max (jnp.argmax)
    }
    float s = 0.f;
#pragma unroll
    for (int e = 0; e < NEXP; e++) s += expf(acc[e] + br[e] - mx);
    idx[t] = best;
    gate[t] = 1.f / s;
    atomicAdd(&ctrl[best], 1);
  }
}

// ctrl layout (ints): [0..7] counts, [8..16] offsets, [17..24] fill, [25..33] tile_start
__global__ void scan_k(int* __restrict__ ctrl) {
  int off = 0, ts = 0;
  ctrl[8] = 0; ctrl[25] = 0;
  for (int e = 0; e < NEXP; e++) {
    off += ctrl[e];                 ctrl[9 + e]  = off;
    ts  += (ctrl[e] + 127) >> 7;    ctrl[26 + e] = ts;
  }
}

// ---------------- scatter tokens to expert-sorted order, fp32 -> bf16 ----------------
__global__ __launch_bounds__(256) void scatter_k(
    const float* __restrict__ x, const int* __restrict__ idx,
    const float* __restrict__ gate, int* __restrict__ ctrl,
    unsigned short* __restrict__ Xb, int* __restrict__ token_dst,
    float* __restrict__ gate_p) {
  __shared__ int s_pos;
  int t = blockIdx.x;
  if (threadIdx.x == 0) {
    int e = idx[t];
    s_pos = ctrl[8 + e] + atomicAdd(&ctrl[17 + e], 1);
  }
  __syncthreads();
  int pos = s_pos;
  if (threadIdx.x == 0) { token_dst[pos] = t; gate_p[pos] = gate[t]; }
  float4 v = ((const float4*)(x + (size_t)t * DIM))[threadIdx.x];
  ushort4 o;
  o.x = f2b(v.x); o.y = f2b(v.y); o.z = f2b(v.z); o.w = f2b(v.w);
  ((ushort4*)(Xb + (size_t)pos * DIM))[threadIdx.x] = o;
}

// ---------------- transpose + fp32->bf16: in [R][C] -> out [C][R] ----------------
__global__ __launch_bounds__(256) void transpose_cvt_k(
    const float* __restrict__ in, unsigned short* __restrict__ out,
    int R, int C) {
  __shared__ float tile[32][33];
  size_t base = (size_t)blockIdx.z * (size_t)R * (size_t)C;
  int c0 = blockIdx.x * 32, r0 = blockIdx.y * 32;
  int tx = threadIdx.x & 31, ty = threadIdx.x >> 5;  // ty 0..7
#pragma unroll
  for (int k = 0; k < 32; k += 8)
    tile[ty + k][tx] = in[base + (size_t)(r0 + ty + k) * C + (c0 + tx)];
  __syncthreads();
#pragma unroll
  for (int k = 0; k < 32; k += 8)
    out[base + (size_t)(c0 + ty + k) * R + (r0 + tx)] = f2b(tile[tx][ty + k]);
}

// ---------------- grouped GEMM1: H = gelu(Xb @ W1^T' + b1), bf16 out ----------------
// A = Xb [M][DIM] bf16 (expert-sorted rows), B = W1b[e] [FDIM][DIM] bf16 (K-contig)
__global__ __launch_bounds__(256) void gemm1_k(
    const unsigned short* __restrict__ Xb, const unsigned short* __restrict__ W1b,
    const float* __restrict__ b1, unsigned short* __restrict__ H,
    const int* __restrict__ ctrl) {
  __shared__ unsigned short A_lds[128 * 40];
  __shared__ unsigned short B_lds[128 * 40];
  int mt = blockIdx.x;
  if (mt >= ctrl[33]) return;
  int e = 0;
  while (ctrl[26 + e] <= mt) e++;
  int mt_local = mt - ctrl[25 + e];
  int m0 = ctrl[8 + e] + mt_local * 128;
  int cnt = ctrl[e] - mt_local * 128; if (cnt > 128) cnt = 128;
  int c0 = blockIdx.y * 128;
  const unsigned short* B = W1b + (size_t)e * FDIM * DIM;

  int tid = threadIdx.x;
  int lane = tid & 63, wave = tid >> 6;
  int wr = wave >> 1, wc = wave & 1;
  int grp = lane >> 4, m16 = lane & 15;

  floatx4 acc[4][4];
  floatx4 zero = {0.f, 0.f, 0.f, 0.f};
#pragma unroll
  for (int i = 0; i < 4; i++)
#pragma unroll
    for (int j = 0; j < 4; j++) acc[i][j] = zero;

  for (int kk = 0; kk < DIM; kk += 32) {
#pragma unroll
    for (int c = tid; c < 512; c += 256) {
      int r = c >> 2, co = (c & 3) << 3;
      uint4 v = {0u, 0u, 0u, 0u};
      if (r < cnt) v = *(const uint4*)(Xb + (size_t)(m0 + r) * DIM + kk + co);
      *(uint4*)&A_lds[r * 40 + co] = v;
    }
#pragma unroll
    for (int c = tid; c < 512; c += 256) {
      int r = c >> 2, co = (c & 3) << 3;
      uint4 v = *(const uint4*)(B + (size_t)(c0 + r) * DIM + kk + co);
      *(uint4*)&B_lds[r * 40 + co] = v;
    }
    __syncthreads();
    bf16x8 af[4], bfr[4];
#pragma unroll
    for (int i = 0; i < 4; i++)
      af[i] = *(const bf16x8*)&A_lds[(wr * 64 + i * 16 + m16) * 40 + grp * 8];
#pragma unroll
    for (int j = 0; j < 4; j++)
      bfr[j] = *(const bf16x8*)&B_lds[(wc * 64 + j * 16 + m16) * 40 + grp * 8];
#pragma unroll
    for (int i = 0; i < 4; i++)
#pragma unroll
      for (int j = 0; j < 4; j++)
        acc[i][j] = __builtin_amdgcn_mfma_f32_16x16x32_bf16(af[i], bfr[j], acc[i][j], 0, 0, 0);
    __syncthreads();
  }

#pragma unroll
  for (int i = 0; i < 4; i++) {
    int lmBase = wr * 64 + i * 16 + grp * 4;
#pragma unroll
    for (int j = 0; j < 4; j++) {
      int col = c0 + wc * 64 + j * 16 + m16;
      float bias = b1[(size_t)e * FDIM + col];
#pragma unroll
      for (int r = 0; r < 4; r++) {
        int lm = lmBase + r;
        if (lm < cnt) {
          float xv = acc[i][j][r] + bias;
          float g = 0.5f * xv * (1.0f + erff(xv * 0.70710678118654752f));
          H[(size_t)(m0 + lm) * FDIM + col] = f2b(g);
        }
      }
    }
  }
}

// ---------------- grouped GEMM2: out[token] = (H @ W2' + b2) * gate ----------------
// A = H [M][FDIM] bf16, B = W2b[e] [DIM][FDIM] bf16 (K-contig)
__global__ __launch_bounds__(256) void gemm2_k(
    const unsigned short* __restrict__ H, const unsigned short* __restrict__ W2b,
    const float* __restrict__ b2, float* __restrict__ out,
    const int* __restrict__ token_dst, const float* __restrict__ gate_p,
    const int* __restrict__ ctrl) {
  __shared__ unsigned short A_lds[128 * 40];
  __shared__ unsigned short B_lds[128 * 40];
  int mt = blockIdx.x;
  if (mt >= ctrl[33]) return;
  int e = 0;
  while (ctrl[26 + e] <= mt) e++;
  int mt_local = mt - ctrl[25 + e];
  int m0 = ctrl[8 + e] + mt_local * 128;
  int cnt = ctrl[e] - mt_local * 128; if (cnt > 128) cnt = 128;
  int c0 = blockIdx.y * 128;
  const unsigned short* B = W2b + (size_t)e * DIM * FDIM;

  int tid = threadIdx.x;
  int lane = tid & 63, wave = tid >> 6;
  int wr = wave >> 1, wc = wave & 1;
  int grp = lane >> 4, m16 = lane & 15;

  floatx4 acc[4][4];
  floatx4 zero = {0.f, 0.f, 0.f, 0.f};
#pragma unroll
  for (int i = 0; i < 4; i++)
#pragma unroll
    for (int j = 0; j < 4; j++) acc[i][j] = zero;

  for (int kk = 0; kk < FDIM; kk += 32) {
#pragma unroll
    for (int c = tid; c < 512; c += 256) {
      int r = c >> 2, co = (c & 3) << 3;
      uint4 v = {0u, 0u, 0u, 0u};
      if (r < cnt) v = *(const uint4*)(H + (size_t)(m0 + r) * FDIM + kk + co);
      *(uint4*)&A_lds[r * 40 + co] = v;
    }
#pragma unroll
    for (int c = tid; c < 512; c += 256) {
      int r = c >> 2, co = (c & 3) << 3;
      uint4 v = *(const uint4*)(B + (size_t)(c0 + r) * FDIM + kk + co);
      *(uint4*)&B_lds[r * 40 + co] = v;
    }
    __syncthreads();
    bf16x8 af[4], bfr[4];
#pragma unroll
    for (int i = 0; i < 4; i++)
      af[i] = *(const bf16x8*)&A_lds[(wr * 64 + i * 16 + m16) * 40 + grp * 8];
#pragma unroll
    for (int j = 0; j < 4; j++)
      bfr[j] = *(const bf16x8*)&B_lds[(wc * 64 + j * 16 + m16) * 40 + grp * 8];
#pragma unroll
    for (int i = 0; i < 4; i++)
#pragma unroll
      for (int j = 0; j < 4; j++)
        acc[i][j] = __builtin_amdgcn_mfma_f32_16x16x32_bf16(af[i], bfr[j], acc[i][j], 0, 0, 0);
    __syncthreads();
  }

#pragma unroll
  for (int i = 0; i < 4; i++) {
    int lmBase = wr * 64 + i * 16 + grp * 4;
#pragma unroll
    for (int j = 0; j < 4; j++) {
      int col = c0 + wc * 64 + j * 16 + m16;
      float bias = b2[(size_t)e * DIM + col];
#pragma unroll
      for (int r = 0; r < 4; r++) {
        int lm = lmBase + r;
        if (lm < cnt) {
          int row = m0 + lm;
          int t = token_dst[row];
          out[(size_t)t * DIM + col] = (acc[i][j][r] + bias) * gate_p[row];
        }
      }
    }
  }
}

extern "C" void kernel_launch(void* const* d_in, const int* in_sizes, int n_in,
                              void* d_out, int out_size, void* d_ws, size_t ws_size,
                              hipStream_t stream) {
  const float* x  = (const float*)d_in[0];
  const float* W1 = (const float*)d_in[1];
  const float* b1 = (const float*)d_in[2];
  const float* W2 = (const float*)d_in[3];
  const float* b2 = (const float*)d_in[4];
  const float* Wr = (const float*)d_in[5];
  const float* br = (const float*)d_in[6];
  float* out = (float*)d_out;

  char* w = (char*)d_ws;
  int*   ctrl      = (int*)w;                         // 64 ints (counts/offsets/fill/tiles)
  int*   idx       = (int*)(w + 1024);
  float* gate      = (float*)(w + 1024 + 4 * NTOK);
  int*   token_dst = (int*)(w + 1024 + 8 * NTOK);
  float* gate_p    = (float*)(w + 1024 + 12 * NTOK);
  unsigned short* Xb  = (unsigned short*)(w + (1ull << 18));    // @256KB,  16.8 MB
  unsigned short* H   = (unsigned short*)(w + (20ull << 20));   // @20MB,   67.1 MB
  unsigned short* W1b = (unsigned short*)(w + (88ull << 20));   // @88MB,   67.1 MB
  unsigned short* W2b = (unsigned short*)(w + (156ull << 20));  // @156MB,  67.1 MB

  hipMemsetAsync(ctrl, 0, 256, stream);
  router_k<<<NTOK / 4, 256, 0, stream>>>(x, Wr, br, idx, gate, ctrl);
  scan_k<<<1, 1, 0, stream>>>(ctrl);
  scatter_k<<<NTOK, 256, 0, stream>>>(x, idx, gate, ctrl, Xb, token_dst, gate_p);
  transpose_cvt_k<<<dim3(FDIM / 32, DIM / 32, NEXP), 256, 0, stream>>>(W1, W1b, DIM, FDIM);
  transpose_cvt_k<<<dim3(DIM / 32, FDIM / 32, NEXP), 256, 0, stream>>>(W2, W2b, FDIM, DIM);
  gemm1_k<<<dim3(72, FDIM / 128), 256, 0, stream>>>(Xb, W1b, b1, H, ctrl);
  gemm2_k<<<dim3(72, DIM / 128), 256, 0, stream>>>(H, W2b, b2, out, token_dst, gate_p, ctrl);
}

// Round 2
// 814.348 us; speedup vs baseline: 1.1581x; 1.1581x over previous
//
#include <hip/hip_runtime.h>
#include <stdint.h>
#include <math.h>

#define NTOK 8192
#define DIM  1024
#define FDIM 4096
#define NEXP 8

typedef __bf16 bf16x8 __attribute__((ext_vector_type(8)));
typedef float floatx4 __attribute__((ext_vector_type(4)));
typedef unsigned int u32;

__device__ __forceinline__ unsigned short f2b(float f) {
  union { float f; unsigned u; } v; v.f = f;
  return (unsigned short)((v.u + 0x7fffu + ((v.u >> 16) & 1u)) >> 16);
}

// async 16B/lane global->LDS. LDS dest must be wave-uniform base; lane i lands at base + i*16.
__device__ __forceinline__ void async_cp16(const unsigned short* g, unsigned short* l) {
  __builtin_amdgcn_global_load_lds((__attribute__((address_space(1))) u32*)g,
                                   (__attribute__((address_space(3))) u32*)l, 16, 0, 0);
}

// ---------------- router: logits, argmax, gate, counts ----------------
__global__ __launch_bounds__(256) void router_k(
    const float* __restrict__ x, const float* __restrict__ Wr,
    const float* __restrict__ br, int* __restrict__ idx,
    float* __restrict__ gate, int* __restrict__ ctrl) {
  int t = (int)((blockIdx.x * 256 + threadIdx.x) >> 6);
  int lane = threadIdx.x & 63;
  const float* xr = x + (size_t)t * DIM;
  float acc[NEXP];
#pragma unroll
  for (int e = 0; e < NEXP; e++) acc[e] = 0.f;
#pragma unroll
  for (int k = 0; k < DIM / 64; k++) {
    int d = k * 64 + lane;
    float xv = xr[d];
    const float4* wp = (const float4*)(Wr + (size_t)d * NEXP);
    float4 w0 = wp[0], w1 = wp[1];
    acc[0] += xv * w0.x; acc[1] += xv * w0.y;
    acc[2] += xv * w0.z; acc[3] += xv * w0.w;
    acc[4] += xv * w1.x; acc[5] += xv * w1.y;
    acc[6] += xv * w1.z; acc[7] += xv * w1.w;
  }
#pragma unroll
  for (int off = 32; off > 0; off >>= 1) {
#pragma unroll
    for (int e = 0; e < NEXP; e++) acc[e] += __shfl_xor(acc[e], off, 64);
  }
  if (lane == 0) {
    float mx = -3.4e38f; int best = 0;
#pragma unroll
    for (int e = 0; e < NEXP; e++) {
      float l = acc[e] + br[e];
      if (l > mx) { mx = l; best = e; }   // '>' keeps first max (jnp.argmax)
    }
    float s = 0.f;
#pragma unroll
    for (int e = 0; e < NEXP; e++) s += expf(acc[e] + br[e] - mx);
    idx[t] = best;
    gate[t] = 1.f / s;
    atomicAdd(&ctrl[best], 1);
  }
}

// ctrl layout (ints): [0..7] counts, [8..16] offsets, [17..24] fill, [25..33] tile_start
__global__ void scan_k(int* __restrict__ ctrl) {
  int off = 0, ts = 0;
  ctrl[8] = 0; ctrl[25] = 0;
  for (int e = 0; e < NEXP; e++) {
    off += ctrl[e];                 ctrl[9 + e]  = off;
    ts  += (ctrl[e] + 127) >> 7;    ctrl[26 + e] = ts;
  }
}

// ---------------- scatter tokens to expert-sorted order, fp32 -> bf16 ----------------
__global__ __launch_bounds__(256) void scatter_k(
    const float* __restrict__ x, const int* __restrict__ idx,
    const float* __restrict__ gate, int* __restrict__ ctrl,
    unsigned short* __restrict__ Xb, int* __restrict__ token_dst,
    float* __restrict__ gate_p) {
  __shared__ int s_pos;
  int t = blockIdx.x;
  if (threadIdx.x == 0) {
    int e = idx[t];
    s_pos = ctrl[8 + e] + atomicAdd(&ctrl[17 + e], 1);
  }
  __syncthreads();
  int pos = s_pos;
  if (threadIdx.x == 0) { token_dst[pos] = t; gate_p[pos] = gate[t]; }
  float4 v = ((const float4*)(x + (size_t)t * DIM))[threadIdx.x];
  ushort4 o;
  o.x = f2b(v.x); o.y = f2b(v.y); o.z = f2b(v.z); o.w = f2b(v.w);
  ((ushort4*)(Xb + (size_t)pos * DIM))[threadIdx.x] = o;
}

// ---------------- transpose + fp32->bf16: in [R][C] -> out [C][R], 64x64 tiles ----------------
__global__ __launch_bounds__(256) void transpose_cvt_k(
    const float* __restrict__ in, unsigned short* __restrict__ out,
    int R, int C) {
  __shared__ float tile[64][65];
  size_t base = (size_t)blockIdx.z * (size_t)R * (size_t)C;
  int c0 = blockIdx.x * 64, r0 = blockIdx.y * 64;
  int t = threadIdx.x;
  int rr = t >> 4, cc = (t & 15) * 4;
#pragma unroll
  for (int k = 0; k < 64; k += 16) {
    float4 v = *(const float4*)&in[base + (size_t)(r0 + rr + k) * C + c0 + cc];
    tile[rr + k][cc] = v.x; tile[rr + k][cc + 1] = v.y;
    tile[rr + k][cc + 2] = v.z; tile[rr + k][cc + 3] = v.w;
  }
  __syncthreads();
  int cr = t >> 4, rb = (t & 15) * 4;
#pragma unroll
  for (int k = 0; k < 64; k += 16) {
    ushort4 o;
    o.x = f2b(tile[rb + 0][cr + k]); o.y = f2b(tile[rb + 1][cr + k]);
    o.z = f2b(tile[rb + 2][cr + k]); o.w = f2b(tile[rb + 3][cr + k]);
    *(ushort4*)&out[base + (size_t)(c0 + cr + k) * R + r0 + rb] = o;
  }
}

// ---------------- grouped GEMM, m97 structure ----------------
// A [NTOK][KDIM] bf16 (expert-sorted rows), B [E][NTOT][KDIM] bf16 (K-contig).
// 128x128 tile, BK=64, 4 waves each 64x64. global_load_lds staging with XOR chunk swizzle:
// physical 16B-chunk position p = chunk ^ (row&7)  -> ds_read_b128 hits all 8 bank groups.
template <int KDIM, int NTOT, bool IS_G1>
__global__ __launch_bounds__(256) void gemm_k(
    const unsigned short* __restrict__ Amat, const unsigned short* __restrict__ Bmat,
    const float* __restrict__ bias, unsigned short* __restrict__ Hout,
    float* __restrict__ Fout, const int* __restrict__ token_dst,
    const float* __restrict__ gate_p, const int* __restrict__ ctrl) {
  __shared__ unsigned short lds[16384];   // A: [0,8192), B: [8192,16384)
  unsigned short* A_lds = lds;
  unsigned short* B_lds = lds + 8192;

  int mt = blockIdx.y;
  if (mt >= ctrl[33]) return;
  int e = 0;
  while (e < 7 && ctrl[26 + e] <= mt) e++;
  int mt_local = mt - ctrl[25 + e];
  int m0 = ctrl[8 + e] + mt_local * 128;
  int cnt = ctrl[e] - mt_local * 128; if (cnt > 128) cnt = 128;
  int c0 = blockIdx.x * 128;
  const unsigned short* B = Bmat + (size_t)e * NTOT * KDIM;

  int tid = threadIdx.x;
  int lane = tid & 63, wave = tid >> 6;
  int wr = wave >> 1, wc = wave & 1;
  int grp = lane >> 4, m16 = lane & 15;

  // staging source pointers (per-lane), LDS dests (wave-uniform)
  int lr = lane >> 3;                 // row within 8-row issue
  int cchunk = (lane & 7) ^ lr;       // swizzled source chunk
  const unsigned short* srcA[4];
  const unsigned short* srcB[4];
  unsigned short* dstA[4];
  unsigned short* dstB[4];
#pragma unroll
  for (int q = 0; q < 4; q++) {
    int brow = wave * 32 + q * 8;
    int arow = m0 + brow + lr; if (arow > NTOK - 1) arow = NTOK - 1;   // clamp partial tile
    srcA[q] = Amat + (size_t)arow * KDIM + cchunk * 8;
    srcB[q] = B + (size_t)(c0 + brow + lr) * KDIM + cchunk * 8;
    dstA[q] = A_lds + brow * 64;
    dstB[q] = B_lds + brow * 64;
  }

  floatx4 acc[4][4];
  floatx4 zero = {0.f, 0.f, 0.f, 0.f};
#pragma unroll
  for (int i = 0; i < 4; i++)
#pragma unroll
    for (int j = 0; j < 4; j++) acc[i][j] = zero;

  int x7 = m16 & 7;
  int rowA[4], rowB[4];
#pragma unroll
  for (int i = 0; i < 4; i++) {
    rowA[i] = (wr * 64 + i * 16 + m16) * 64;
    rowB[i] = (wc * 64 + i * 16 + m16) * 64;
  }

  for (int kk = 0; kk < KDIM; kk += 64) {
#pragma unroll
    for (int q = 0; q < 4; q++) async_cp16(srcA[q], dstA[q]);
#pragma unroll
    for (int q = 0; q < 4; q++) async_cp16(srcB[q], dstB[q]);
#pragma unroll
    for (int q = 0; q < 4; q++) { srcA[q] += 64; srcB[q] += 64; }
    __syncthreads();   // drains vmcnt (global_load_lds) + barrier
    bf16x8 af[2][4], bfr[2][4];
#pragma unroll
    for (int h = 0; h < 2; h++) {
      int off = (((h << 2) | grp) ^ x7) << 3;
#pragma unroll
      for (int i = 0; i < 4; i++) {
        af[h][i]  = *(const bf16x8*)&A_lds[rowA[i] + off];
        bfr[h][i] = *(const bf16x8*)&B_lds[rowB[i] + off];
      }
    }
#pragma unroll
    for (int h = 0; h < 2; h++)
#pragma unroll
      for (int i = 0; i < 4; i++)
#pragma unroll
        for (int j = 0; j < 4; j++)
          acc[i][j] = __builtin_amdgcn_mfma_f32_16x16x32_bf16(af[h][i], bfr[h][j], acc[i][j], 0, 0, 0);
    __syncthreads();
  }

  float bs[4];
#pragma unroll
  for (int j = 0; j < 4; j++) bs[j] = bias[(size_t)e * NTOT + c0 + wc * 64 + j * 16 + m16];

  if (IS_G1) {
    // gelu -> stage wave's 64x64 bf16 tile in LDS -> coalesced uint4 stores
    unsigned short* st = lds + wave * 4096;
#pragma unroll
    for (int i = 0; i < 4; i++)
#pragma unroll
      for (int j = 0; j < 4; j++)
#pragma unroll
        for (int r = 0; r < 4; r++) {
          float xv = acc[i][j][r] + bs[j];
          float g = 0.5f * xv * (1.0f + erff(xv * 0.70710678118654752f));
          st[(i * 16 + grp * 4 + r) * 64 + j * 16 + m16] = f2b(g);
        }
    __syncthreads();
    int lr8 = lane >> 3, c8 = (lane & 7) * 8;
    int colb = c0 + wc * 64 + c8;
#pragma unroll
    for (int rr = 0; rr < 8; rr++) {
      int row = rr * 8 + lr8;
      int gm = wr * 64 + row;
      if (gm < cnt)
        *(uint4*)&Hout[(size_t)(m0 + gm) * FDIM + colb] = *(const uint4*)&st[row * 64 + c8];
    }
  } else {
    // bias + gate, scatter rows back to token order
#pragma unroll
    for (int i = 0; i < 4; i++) {
      int rb = wr * 64 + i * 16 + grp * 4;
#pragma unroll
      for (int r = 0; r < 4; r++) {
        int lm = rb + r;
        if (lm < cnt) {
          int row = m0 + lm;
          int t = token_dst[row];
          float gv = gate_p[row];
#pragma unroll
          for (int j = 0; j < 4; j++) {
            int col = c0 + wc * 64 + j * 16 + m16;
            Fout[(size_t)t * DIM + col] = (acc[i][j][r] + bs[j]) * gv;
          }
        }
      }
    }
  }
}

extern "C" void kernel_launch(void* const* d_in, const int* in_sizes, int n_in,
                              void* d_out, int out_size, void* d_ws, size_t ws_size,
                              hipStream_t stream) {
  const float* x  = (const float*)d_in[0];
  const float* W1 = (const float*)d_in[1];
  const float* b1 = (const float*)d_in[2];
  const float* W2 = (const float*)d_in[3];
  const float* b2 = (const float*)d_in[4];
  const float* Wr = (const float*)d_in[5];
  const float* br = (const float*)d_in[6];
  float* out = (float*)d_out;

  char* w = (char*)d_ws;
  int*   ctrl      = (int*)w;
  int*   idx       = (int*)(w + 1024);
  float* gate      = (float*)(w + 1024 + 4 * NTOK);
  int*   token_dst = (int*)(w + 1024 + 8 * NTOK);
  float* gate_p    = (float*)(w + 1024 + 12 * NTOK);
  unsigned short* Xb  = (unsigned short*)(w + (1ull << 18));    // 16.8 MB
  unsigned short* H   = (unsigned short*)(w + (20ull << 20));   // 67.1 MB
  unsigned short* W1b = (unsigned short*)(w + (88ull << 20));   // 67.1 MB, [E][F][D]
  unsigned short* W2b = (unsigned short*)(w + (156ull << 20));  // 67.1 MB, [E][D][F]

  hipMemsetAsync(ctrl, 0, 256, stream);
  router_k<<<NTOK / 4, 256, 0, stream>>>(x, Wr, br, idx, gate, ctrl);
  scan_k<<<1, 1, 0, stream>>>(ctrl);
  scatter_k<<<NTOK, 256, 0, stream>>>(x, idx, gate, ctrl, Xb, token_dst, gate_p);
  transpose_cvt_k<<<dim3(FDIM / 64, DIM / 64, NEXP), 256, 0, stream>>>(W1, W1b, DIM, FDIM);
  transpose_cvt_k<<<dim3(DIM / 64, FDIM / 64, NEXP), 256, 0, stream>>>(W2, W2b, FDIM, DIM);
  // x = N-tile (fast-varying -> consecutive blocks share the A m-tile in L2), y = m-tile
  gemm_k<DIM, FDIM, true><<<dim3(FDIM / 128, 72), 256, 0, stream>>>(
      Xb, W1b, b1, H, nullptr, nullptr, nullptr, ctrl);
  gemm_k<FDIM, DIM, false><<<dim3(DIM / 128, 72), 256, 0, stream>>>(
      H, W2b, b2, nullptr, out, token_dst, gate_p, ctrl);
}

// Round 3
// 794.487 us; speedup vs baseline: 1.1871x; 1.0250x over previous
//
#include <hip/hip_runtime.h>
#include <stdint.h>
#include <math.h>

#define NTOK 8192
#define DIM  1024
#define FDIM 4096
#define NEXP 8

typedef __bf16 bf16x8 __attribute__((ext_vector_type(8)));
typedef float floatx4 __attribute__((ext_vector_type(4)));
typedef unsigned int u32;

__device__ __forceinline__ unsigned short f2b(float f) {
  union { float f; unsigned u; } v; v.f = f;
  return (unsigned short)((v.u + 0x7fffu + ((v.u >> 16) & 1u)) >> 16);
}

__device__ __forceinline__ float gelu_f(float x) {
  // tanh-form GELU via sigmoid: 0.5x(1+tanh(u)) = x*sigma(2u). One v_exp_f32.
  float u = 1.5957691216f * x * (1.0f + 0.044715f * x * x);
  return x / (1.0f + __expf(-u));
}

// async 16B/lane global->LDS. LDS dest is wave-uniform base; lane i lands at base + i*16.
__device__ __forceinline__ void async_cp16(const unsigned short* g, unsigned short* l) {
  __builtin_amdgcn_global_load_lds((__attribute__((address_space(1))) u32*)g,
                                   (__attribute__((address_space(3))) u32*)l, 16, 0, 0);
}

// ---------------- router ----------------
__global__ __launch_bounds__(256) void router_k(
    const float* __restrict__ x, const float* __restrict__ Wr,
    const float* __restrict__ br, int* __restrict__ idx,
    float* __restrict__ gate, int* __restrict__ ctrl) {
  int t = (int)((blockIdx.x * 256 + threadIdx.x) >> 6);
  int lane = threadIdx.x & 63;
  const float* xr = x + (size_t)t * DIM;
  float acc[NEXP];
#pragma unroll
  for (int e = 0; e < NEXP; e++) acc[e] = 0.f;
#pragma unroll
  for (int k = 0; k < DIM / 64; k++) {
    int d = k * 64 + lane;
    float xv = xr[d];
    const float4* wp = (const float4*)(Wr + (size_t)d * NEXP);
    float4 w0 = wp[0], w1 = wp[1];
    acc[0] += xv * w0.x; acc[1] += xv * w0.y;
    acc[2] += xv * w0.z; acc[3] += xv * w0.w;
    acc[4] += xv * w1.x; acc[5] += xv * w1.y;
    acc[6] += xv * w1.z; acc[7] += xv * w1.w;
  }
#pragma unroll
  for (int off = 32; off > 0; off >>= 1) {
#pragma unroll
    for (int e = 0; e < NEXP; e++) acc[e] += __shfl_xor(acc[e], off, 64);
  }
  if (lane == 0) {
    float mx = -3.4e38f; int best = 0;
#pragma unroll
    for (int e = 0; e < NEXP; e++) {
      float l = acc[e] + br[e];
      if (l > mx) { mx = l; best = e; }
    }
    float s = 0.f;
#pragma unroll
    for (int e = 0; e < NEXP; e++) s += expf(acc[e] + br[e] - mx);
    idx[t] = best;
    gate[t] = 1.f / s;
    atomicAdd(&ctrl[best], 1);
  }
}

// ctrl: [0..7] counts, [8..16] offsets, [17..24] fill, [25..33] tile_start
__global__ void scan_k(int* __restrict__ ctrl) {
  int off = 0, ts = 0;
  ctrl[8] = 0; ctrl[25] = 0;
  for (int e = 0; e < NEXP; e++) {
    off += ctrl[e];                 ctrl[9 + e]  = off;
    ts  += (ctrl[e] + 127) >> 7;    ctrl[26 + e] = ts;
  }
}

// ---------------- scatter tokens, fp32 -> bf16 ----------------
__global__ __launch_bounds__(256) void scatter_k(
    const float* __restrict__ x, const int* __restrict__ idx,
    const float* __restrict__ gate, int* __restrict__ ctrl,
    unsigned short* __restrict__ Xb, int* __restrict__ token_dst,
    float* __restrict__ gate_p) {
  __shared__ int s_pos;
  int t = blockIdx.x;
  if (threadIdx.x == 0) {
    int e = idx[t];
    s_pos = ctrl[8 + e] + atomicAdd(&ctrl[17 + e], 1);
  }
  __syncthreads();
  int pos = s_pos;
  if (threadIdx.x == 0) { token_dst[pos] = t; gate_p[pos] = gate[t]; }
  float4 v = ((const float4*)(x + (size_t)t * DIM))[threadIdx.x];
  ushort4 o;
  o.x = f2b(v.x); o.y = f2b(v.y); o.z = f2b(v.z); o.w = f2b(v.w);
  ((ushort4*)(Xb + (size_t)pos * DIM))[threadIdx.x] = o;
}

// ---------------- transpose + cvt: in [R][C] -> out [C][R], 64x64 tiles, 16B stores ----------------
__global__ __launch_bounds__(256) void transpose_cvt_k(
    const float* __restrict__ in, unsigned short* __restrict__ out,
    int R, int C) {
  __shared__ float tile[64][65];
  __shared__ unsigned short obuf[64][72];
  size_t base = (size_t)blockIdx.z * (size_t)R * (size_t)C;
  int c0 = blockIdx.x * 64, r0 = blockIdx.y * 64;
  int t = threadIdx.x;
  int rr = t >> 4, cc = (t & 15) * 4;
#pragma unroll
  for (int k = 0; k < 64; k += 16) {
    float4 v = *(const float4*)&in[base + (size_t)(r0 + rr + k) * C + c0 + cc];
    tile[rr + k][cc] = v.x; tile[rr + k][cc + 1] = v.y;
    tile[rr + k][cc + 2] = v.z; tile[rr + k][cc + 3] = v.w;
  }
  __syncthreads();
  int cr = t >> 4, rb = (t & 15) * 4;
#pragma unroll
  for (int k = 0; k < 64; k += 16) {
    ushort4 o;
    o.x = f2b(tile[rb + 0][cr + k]); o.y = f2b(tile[rb + 1][cr + k]);
    o.z = f2b(tile[rb + 2][cr + k]); o.w = f2b(tile[rb + 3][cr + k]);
    *(ushort4*)&obuf[cr + k][rb] = o;
  }
  __syncthreads();
  int r2 = t >> 3, c8 = (t & 7) * 8;
#pragma unroll
  for (int k = 0; k < 64; k += 32)
    *(uint4*)&out[base + (size_t)(c0 + r2 + k) * R + r0 + c8] = *(const uint4*)&obuf[r2 + k][c8];
}

// ---------------- GEMM1: H = gelu(Xb @ W1b^T + b1) ----------------
__global__ __launch_bounds__(256) void gemm1_k(
    const unsigned short* __restrict__ Amat, const unsigned short* __restrict__ Bmat,
    const float* __restrict__ bias, unsigned short* __restrict__ Hout,
    const int* __restrict__ ctrl) {
  __shared__ unsigned short lds[16384];
  unsigned short* A_lds = lds;
  unsigned short* B_lds = lds + 8192;

  int mt = blockIdx.y;
  if (mt >= ctrl[33]) return;
  int e = 0;
  while (e < 7 && ctrl[26 + e] <= mt) e++;
  int mt_local = mt - ctrl[25 + e];
  int m0 = ctrl[8 + e] + mt_local * 128;
  int cnt = ctrl[e] - mt_local * 128; if (cnt > 128) cnt = 128;
  int c0 = blockIdx.x * 128;
  const unsigned short* B = Bmat + (size_t)e * FDIM * DIM;

  int tid = threadIdx.x;
  int lane = tid & 63, wave = tid >> 6;
  int wr = wave >> 1, wc = wave & 1;
  int grp = lane >> 4, m16 = lane & 15;

  int lr = lane >> 3;
  int cchunk = (lane & 7) ^ lr;
  const unsigned short* srcA[4];
  const unsigned short* srcB[4];
  unsigned short* dstA[4];
  unsigned short* dstB[4];
#pragma unroll
  for (int q = 0; q < 4; q++) {
    int brow = wave * 32 + q * 8;
    int arow = m0 + brow + lr; if (arow > NTOK - 1) arow = NTOK - 1;
    srcA[q] = Amat + (size_t)arow * DIM + cchunk * 8;
    srcB[q] = B + (size_t)(c0 + brow + lr) * DIM + cchunk * 8;
    dstA[q] = A_lds + brow * 64;
    dstB[q] = B_lds + brow * 64;
  }

  floatx4 acc[4][4];
  floatx4 zero = {0.f, 0.f, 0.f, 0.f};
#pragma unroll
  for (int i = 0; i < 4; i++)
#pragma unroll
    for (int j = 0; j < 4; j++) acc[i][j] = zero;

  int x7 = m16 & 7;
  int rowA[4], rowB[4];
#pragma unroll
  for (int i = 0; i < 4; i++) {
    rowA[i] = (wr * 64 + i * 16 + m16) * 64;
    rowB[i] = (wc * 64 + i * 16 + m16) * 64;
  }

  for (int kk = 0; kk < DIM; kk += 64) {
#pragma unroll
    for (int q = 0; q < 4; q++) async_cp16(srcA[q], dstA[q]);
#pragma unroll
    for (int q = 0; q < 4; q++) async_cp16(srcB[q], dstB[q]);
#pragma unroll
    for (int q = 0; q < 4; q++) { srcA[q] += 64; srcB[q] += 64; }
    __syncthreads();
    bf16x8 af[2][4], bfr[2][4];
#pragma unroll
    for (int h = 0; h < 2; h++) {
      int off = (((h << 2) | grp) ^ x7) << 3;
#pragma unroll
      for (int i = 0; i < 4; i++) {
        af[h][i]  = *(const bf16x8*)&A_lds[rowA[i] + off];
        bfr[h][i] = *(const bf16x8*)&B_lds[rowB[i] + off];
      }
    }
#pragma unroll
    for (int h = 0; h < 2; h++)
#pragma unroll
      for (int i = 0; i < 4; i++)
#pragma unroll
        for (int j = 0; j < 4; j++)
          acc[i][j] = __builtin_amdgcn_mfma_f32_16x16x32_bf16(af[h][i], bfr[h][j], acc[i][j], 0, 0, 0);
    __syncthreads();
  }

  float bs[4];
#pragma unroll
  for (int j = 0; j < 4; j++) bs[j] = bias[(size_t)e * FDIM + c0 + wc * 64 + j * 16 + m16];

  unsigned short* st = lds + wave * 4096;
#pragma unroll
  for (int i = 0; i < 4; i++)
#pragma unroll
    for (int j = 0; j < 4; j++)
#pragma unroll
      for (int r = 0; r < 4; r++)
        st[(i * 16 + grp * 4 + r) * 64 + j * 16 + m16] = f2b(gelu_f(acc[i][j][r] + bs[j]));
  __syncthreads();
  int lr8 = lane >> 3, c8 = (lane & 7) * 8;
  int colb = c0 + wc * 64 + c8;
#pragma unroll
  for (int rr = 0; rr < 8; rr++) {
    int row = rr * 8 + lr8;
    int gm = wr * 64 + row;
    if (gm < cnt)
      *(uint4*)&Hout[(size_t)(m0 + gm) * FDIM + colb] = *(const uint4*)&st[row * 64 + c8];
  }
}

// ---------------- GEMM2 split-K chunk: P[chunk] = H[:, chunk] @ W2b[:, chunk]^T ----------------
__global__ __launch_bounds__(256) void gemm2_k(
    const unsigned short* __restrict__ Hmat, const unsigned short* __restrict__ W2b,
    float* __restrict__ P, const int* __restrict__ ctrl) {
  __shared__ unsigned short lds[16384];
  unsigned short* A_lds = lds;
  unsigned short* B_lds = lds + 8192;

  int mt = blockIdx.y;
  if (mt >= ctrl[33]) return;
  int e = 0;
  while (e < 7 && ctrl[26 + e] <= mt) e++;
  int mt_local = mt - ctrl[25 + e];
  int m0 = ctrl[8 + e] + mt_local * 128;
  int cnt = ctrl[e] - mt_local * 128; if (cnt > 128) cnt = 128;
  int c0 = blockIdx.x * 128;
  int chunk = blockIdx.z;
  int k0 = chunk * (FDIM / 2);
  const unsigned short* B = W2b + (size_t)e * DIM * FDIM + k0;
  const unsigned short* A = Hmat + k0;
  float* Pc = P + (size_t)chunk * NTOK * DIM;

  int tid = threadIdx.x;
  int lane = tid & 63, wave = tid >> 6;
  int wr = wave >> 1, wc = wave & 1;
  int grp = lane >> 4, m16 = lane & 15;

  int lr = lane >> 3;
  int cchunk = (lane & 7) ^ lr;
  const unsigned short* srcA[4];
  const unsigned short* srcB[4];
  unsigned short* dstA[4];
  unsigned short* dstB[4];
#pragma unroll
  for (int q = 0; q < 4; q++) {
    int brow = wave * 32 + q * 8;
    int arow = m0 + brow + lr; if (arow > NTOK - 1) arow = NTOK - 1;
    srcA[q] = A + (size_t)arow * FDIM + cchunk * 8;
    srcB[q] = B + (size_t)(c0 + brow + lr) * FDIM + cchunk * 8;
    dstA[q] = A_lds + brow * 64;
    dstB[q] = B_lds + brow * 64;
  }

  floatx4 acc[4][4];
  floatx4 zero = {0.f, 0.f, 0.f, 0.f};
#pragma unroll
  for (int i = 0; i < 4; i++)
#pragma unroll
    for (int j = 0; j < 4; j++) acc[i][j] = zero;

  int x7 = m16 & 7;
  int rowA[4], rowB[4];
#pragma unroll
  for (int i = 0; i < 4; i++) {
    rowA[i] = (wr * 64 + i * 16 + m16) * 64;
    rowB[i] = (wc * 64 + i * 16 + m16) * 64;
  }

  for (int kk = 0; kk < FDIM / 2; kk += 64) {
#pragma unroll
    for (int q = 0; q < 4; q++) async_cp16(srcA[q], dstA[q]);
#pragma unroll
    for (int q = 0; q < 4; q++) async_cp16(srcB[q], dstB[q]);
#pragma unroll
    for (int q = 0; q < 4; q++) { srcA[q] += 64; srcB[q] += 64; }
    __syncthreads();
    bf16x8 af[2][4], bfr[2][4];
#pragma unroll
    for (int h = 0; h < 2; h++) {
      int off = (((h << 2) | grp) ^ x7) << 3;
#pragma unroll
      for (int i = 0; i < 4; i++) {
        af[h][i]  = *(const bf16x8*)&A_lds[rowA[i] + off];
        bfr[h][i] = *(const bf16x8*)&B_lds[rowB[i] + off];
      }
    }
#pragma unroll
    for (int h = 0; h < 2; h++)
#pragma unroll
      for (int i = 0; i < 4; i++)
#pragma unroll
        for (int j = 0; j < 4; j++)
          acc[i][j] = __builtin_amdgcn_mfma_f32_16x16x32_bf16(af[h][i], bfr[h][j], acc[i][j], 0, 0, 0);
    __syncthreads();
  }

#pragma unroll
  for (int i = 0; i < 4; i++) {
    int rb = wr * 64 + i * 16 + grp * 4;
#pragma unroll
    for (int r = 0; r < 4; r++) {
      int lm = rb + r;
      if (lm < cnt) {
#pragma unroll
        for (int j = 0; j < 4; j++) {
          int col = c0 + wc * 64 + j * 16 + m16;
          Pc[(size_t)(m0 + lm) * DIM + col] = acc[i][j][r];
        }
      }
    }
  }
}

// ---------------- reduce: out[token] = (P0+P1+b2)*gate ----------------
__global__ __launch_bounds__(256) void reduce_k(
    const float* __restrict__ P, const float* __restrict__ b2,
    float* __restrict__ out, const int* __restrict__ token_dst,
    const float* __restrict__ gate_p, const int* __restrict__ ctrl) {
  int row = blockIdx.x;
  int e = 0;
  while (e < 7 && ctrl[9 + e] <= row) e++;
  int t = token_dst[row];
  float g = gate_p[row];
  int c = threadIdx.x * 4;
  float4 p0 = *(const float4*)&P[(size_t)row * DIM + c];
  float4 p1 = *(const float4*)&P[(size_t)(NTOK + row) * DIM + c];
  float4 bb = *(const float4*)&b2[(size_t)e * DIM + c];
  float4 o;
  o.x = (p0.x + p1.x + bb.x) * g;
  o.y = (p0.y + p1.y + bb.y) * g;
  o.z = (p0.z + p1.z + bb.z) * g;
  o.w = (p0.w + p1.w + bb.w) * g;
  *(float4*)&out[(size_t)t * DIM + c] = o;
}

extern "C" void kernel_launch(void* const* d_in, const int* in_sizes, int n_in,
                              void* d_out, int out_size, void* d_ws, size_t ws_size,
                              hipStream_t stream) {
  const float* x  = (const float*)d_in[0];
  const float* W1 = (const float*)d_in[1];
  const float* b1 = (const float*)d_in[2];
  const float* W2 = (const float*)d_in[3];
  const float* b2 = (const float*)d_in[4];
  const float* Wr = (const float*)d_in[5];
  const float* br = (const float*)d_in[6];
  float* out = (float*)d_out;

  char* w = (char*)d_ws;
  int*   ctrl      = (int*)w;
  int*   idx       = (int*)(w + 1024);
  float* gate      = (float*)(w + 1024 + 4 * NTOK);
  int*   token_dst = (int*)(w + 1024 + 8 * NTOK);
  float* gate_p    = (float*)(w + 1024 + 12 * NTOK);
  unsigned short* Xb  = (unsigned short*)(w + (1ull << 18));    // 16.8 MB
  unsigned short* H   = (unsigned short*)(w + (20ull << 20));   // 67.1 MB
  unsigned short* W1b = (unsigned short*)(w + (88ull << 20));   // 67.1 MB, dead after gemm1
  unsigned short* W2b = (unsigned short*)(w + (156ull << 20));  // 67.1 MB
  float*          P   = (float*)(w + (88ull << 20));            // 2x33.5 MB fp32, overlays W1b

  hipMemsetAsync(ctrl, 0, 256, stream);
  router_k<<<NTOK / 4, 256, 0, stream>>>(x, Wr, br, idx, gate, ctrl);
  scan_k<<<1, 1, 0, stream>>>(ctrl);
  scatter_k<<<NTOK, 256, 0, stream>>>(x, idx, gate, ctrl, Xb, token_dst, gate_p);
  transpose_cvt_k<<<dim3(FDIM / 64, DIM / 64, NEXP), 256, 0, stream>>>(W1, W1b, DIM, FDIM);
  transpose_cvt_k<<<dim3(DIM / 64, FDIM / 64, NEXP), 256, 0, stream>>>(W2, W2b, FDIM, DIM);
  gemm1_k<<<dim3(FDIM / 128, 72), 256, 0, stream>>>(Xb, W1b, b1, H, ctrl);
  gemm2_k<<<dim3(DIM / 128, 72, 2), 256, 0, stream>>>(H, W2b, P, ctrl);
  reduce_k<<<NTOK, 256, 0, stream>>>(P, b2, out, token_dst, gate_p, ctrl);
}